// Round 9
// baseline (51.866 us; speedup 1.0000x reference)
//
#include <hip/hip_runtime.h>
#include <stdint.h>

// DN4 image-to-class via bf16 MFMA, round 9: fragment-layout staging.
// prep:     normalize descriptors and store them in MFMA fragment order:
//           per 16-descriptor block, 1024 ushorts: [ck][kg*16+row][8]
//           -> every A-load / LDS B-read is a contiguous lane*16 stream.
// dn4_mfma: grid 750 = (c, b, M-half); 8 waves x 32 queries; 128-row support
//           tiles double-buffered in LDS via linear global_load_lds.
// dn4_topq: merge 2 halves x top-3, shfl-bitonic descending sort 256 -> top-64.

#define C_CLS 5
#define SHOTS 5
#define DIM 64
#define HW 256
#define NQ 75
#define K1 3
#define K2 64
#define M_TOT 1280
#define MHALF 640
#define TROWS 128
#define NIT (MHALF / TROWS)   // 5
#define QG 2                  // 16-query groups per wave

using bf16x8 = __attribute__((ext_vector_type(8))) short;
using u32x4  = __attribute__((ext_vector_type(4))) unsigned int;
using f32x4  = __attribute__((ext_vector_type(4))) float;

typedef __attribute__((address_space(1))) const unsigned int GU32;
typedef __attribute__((address_space(3))) unsigned int LU32;

__device__ __forceinline__ void gload16(const void* g, void* l) {
    __builtin_amdgcn_global_load_lds((GU32*)g, (LU32*)l, 16, 0, 0);
}

__device__ inline unsigned short f2bf(float x) {
    uint32_t u = __float_as_uint(x);
    u += 0x7FFF + ((u >> 16) & 1);          // RNE
    return (unsigned short)(u >> 16);
}

// branchless sorted-triple insert; all 3 ops independent (read old values)
__device__ __forceinline__ void ins3(float v, float& t0, float& t1, float& t2) {
    t2 = __builtin_amdgcn_fmed3f(v, t1, t2);
    t1 = __builtin_amdgcn_fmed3f(v, t0, t1);
    t0 = fmaxf(t0, v);
}

// 400 blocks x 256 threads; each wave: 16 descriptors x 4 d-groups of 16.
// Fragment block contract (1024 us per 16 descriptors):
//   us[ck*512 + (kg*16 + row)*8 + j] = elem(row, k = ck*32 + kg*8 + j)
__global__ __launch_bounds__(256)
void prep(const float* __restrict__ support, const float* __restrict__ query,
          unsigned short* __restrict__ Sn, unsigned short* __restrict__ Qn) {
    const int tid  = threadIdx.x;
    const int wv   = tid >> 6, lane = tid & 63;
    const int dg   = lane >> 4, dl = lane & 15;
    const int bid  = blockIdx.x;
    const float* src;
    unsigned short* dstblk;     // this thread's fragment block base
    if (bid < NQ * 4) {
        const int b    = bid >> 2;
        const int desc = (bid & 3) * 64 + wv * 16 + dl;
        src    = query + (size_t)b * DIM * HW + desc;
        dstblk = Qn + (size_t)b * 16384 + (size_t)((bid & 3) * 4 + wv) * 1024;
    } else {
        const int sb   = bid - NQ * 4;
        const int cs   = sb >> 2;                      // c*SHOTS + s
        const int desc = (sb & 3) * 64 + wv * 16 + dl;
        const int c = cs / SHOTS, s = cs % SHOTS;
        src    = support + (size_t)cs * DIM * HW + desc;
        dstblk = Sn + (size_t)c * 81920 + (size_t)(s * 16 + (sb & 3) * 4 + wv) * 1024;
    }
    float v[16];
    float nrm = 0.f;
#pragma unroll
    for (int i = 0; i < 16; ++i) {
        const float x = src[(dg * 16 + i) * HW];
        v[i] = x; nrm = fmaf(x, x, nrm);
    }
    nrm += __shfl_xor(nrm, 16, 64);
    nrm += __shfl_xor(nrm, 32, 64);
    const float inv = rsqrtf(nrm);
    uint32_t p[8];
#pragma unroll
    for (int j = 0; j < 8; ++j)
        p[j] = (uint32_t)f2bf(v[2 * j] * inv) | ((uint32_t)f2bf(v[2 * j + 1] * inv) << 16);
    // dims dg*16 + q*8 + [0..8) -> ck = dg>>1, kg = (dg&1)*2 + q, row = dl
    const int ck = dg >> 1;
#pragma unroll
    for (int q = 0; q < 2; ++q) {
        const int kg = (dg & 1) * 2 + q;
        uint4 wq = {p[q * 4 + 0], p[q * 4 + 1], p[q * 4 + 2], p[q * 4 + 3]};
        *(uint4*)(dstblk + ck * 512 + (kg * 16 + dl) * 8) = wq;
    }
}

// grid 750: bid = (c*NQ + b)*2 + half. 512 threads = 8 waves x 32 queries.
__global__ __launch_bounds__(512)
void dn4_mfma(const unsigned short* __restrict__ Sn,
              const unsigned short* __restrict__ Qn,
              float* __restrict__ partial) {
    __shared__ unsigned short sB[2][TROWS * DIM];   // 2 x 16 KB, double-buffered

    const int tid  = threadIdx.x;
    const int lane = tid & 63, w = tid >> 6;        // w in 0..7
    const int c15  = lane & 15, kg = lane >> 4;
    const int bid  = blockIdx.x;
    const int half = bid & 1;
    const int cb   = bid >> 1;
    const int c    = cb / NQ, b = cb % NQ;

    // ---- A fragments: contiguous 1KB wave streams (fragment layout) ----
    bf16x8 aq[QG][2];
    const unsigned short* qf = Qn + (size_t)b * 16384 + (size_t)(w * 2) * 1024;
#pragma unroll
    for (int g = 0; g < QG; ++g)
#pragma unroll
        for (int ck = 0; ck < 2; ++ck)
            aq[g][ck] = __builtin_bit_cast(bf16x8,
                *(const u32x4*)(qf + g * 1024 + ck * 512 + lane * 8));

    float t0[QG][4], t1[QG][4], t2[QG][4];
#pragma unroll
    for (int g = 0; g < QG; ++g)
#pragma unroll
        for (int r = 0; r < 4; ++r) { t0[g][r] = -2.f; t1[g][r] = -2.f; t2[g][r] = -2.f; }

    const f32x4 Z = {0.f, 0.f, 0.f, 0.f};
    const char* tb0 = (const char*)(Sn + (size_t)c * 81920 + (size_t)half * 40960);

    // ---- prologue: stage tile 0 linearly (2 reps x 8 KB) ----
#pragma unroll
    for (int rep = 0; rep < 2; ++rep)
        gload16(tb0 + rep * 8192 + tid * 16, (char*)sB[0] + rep * 8192 + w * 1024);
    __syncthreads();

    int cur = 0;
    for (int it = 0; it < NIT; ++it) {
        if (it < NIT - 1) {                       // issue next tile BEFORE compute
            const char* tb = tb0 + (size_t)(it + 1) * 16384;
#pragma unroll
            for (int rep = 0; rep < 2; ++rep)
                gload16(tb + rep * 8192 + tid * 16,
                        (char*)sB[cur ^ 1] + rep * 8192 + w * 1024);
        }
#pragma unroll
        for (int ns = 0; ns < 8; ++ns) {          // 8 blocks of 16 support rows
            const unsigned short* rp = &sB[cur][ns * 1024 + lane * 8];
            const bf16x8 b0 = __builtin_bit_cast(bf16x8, *(const u32x4*)rp);
            const bf16x8 b1 = __builtin_bit_cast(bf16x8, *(const u32x4*)(rp + 512));
#pragma unroll
            for (int g = 0; g < QG; ++g) {
                f32x4 acc = __builtin_amdgcn_mfma_f32_16x16x32_bf16(aq[g][0], b0, Z, 0, 0, 0);
                acc = __builtin_amdgcn_mfma_f32_16x16x32_bf16(aq[g][1], b1, acc, 0, 0, 0);
#pragma unroll
                for (int r = 0; r < 4; ++r)
                    ins3(acc[r], t0[g][r], t1[g][r], t2[g][r]);
            }
        }
        __syncthreads();                          // drains staging vmcnt too
        cur ^= 1;
    }

    // ---- merge across the 16 support-column lanes (c15 bits only) ----
#pragma unroll
    for (int g = 0; g < QG; ++g)
#pragma unroll
        for (int r = 0; r < 4; ++r)
#pragma unroll
            for (int off = 1; off < 16; off <<= 1) {
                const float o0 = __shfl_xor(t0[g][r], off, 64);
                const float o1 = __shfl_xor(t1[g][r], off, 64);
                const float o2 = __shfl_xor(t2[g][r], off, 64);
                ins3(o0, t0[g][r], t1[g][r], t2[g][r]);
                ins3(o1, t0[g][r], t1[g][r], t2[g][r]);
                ins3(o2, t0[g][r], t1[g][r], t2[g][r]);
            }

    if (c15 == 0) {
        float* pbase = partial + ((size_t)(cb * 2 + half) * K1) * HW;
#pragma unroll
        for (int g = 0; g < QG; ++g)
#pragma unroll
            for (int r = 0; r < 4; ++r) {
                const int qloc = (w * 2 + g) * 16 + kg * 4 + r;
                pbase[qloc]          = t0[g][r];
                pbase[HW + qloc]     = t1[g][r];
                pbase[2 * HW + qloc] = t2[g][r];
            }
    }
}

// grid 1125: (c*NQ+b)*3 + ki. Merge 2 halves x top-3, shfl-bitonic sort, write 64.
__global__ __launch_bounds__(256)
void dn4_topq(const float* __restrict__ partial, float* __restrict__ out) {
    __shared__ float sbuf[HW];
    const int tid = threadIdx.x;
    const int bid = blockIdx.x;
    const int ki  = bid % K1;
    const int cb  = bid / K1;

    const float* p = partial + (size_t)cb * 2 * K1 * HW + tid;
    float t0 = -2.f, t1 = -2.f, t2 = -2.f;
#pragma unroll
    for (int h = 0; h < 2; ++h)
#pragma unroll
        for (int r = 0; r < K1; ++r)
            ins3(p[(h * K1 + r) * HW], t0, t1, t2);
    float v = (ki == 0) ? t0 : (ki == 1) ? t1 : t2;

#pragma unroll
    for (int kk = 2; kk <= HW; kk <<= 1) {
#pragma unroll
        for (int j = kk >> 1; j > 0; j >>= 1) {
            const bool keep_max = (((tid & kk) == 0) == ((tid & j) == 0));
            float wv;
            if (j >= 64) {
                sbuf[tid] = v;
                __syncthreads();
                wv = sbuf[tid ^ j];
                __syncthreads();
            } else {
                wv = __shfl_xor(v, j, 64);
            }
            v = keep_max ? fmaxf(v, wv) : fminf(v, wv);
        }
    }
    if (tid < K2) out[(size_t)cb * K1 * K2 + (size_t)ki * K2 + tid] = v;
}

extern "C" void kernel_launch(void* const* d_in, const int* in_sizes, int n_in,
                              void* d_out, int out_size, void* d_ws, size_t ws_size,
                              hipStream_t stream) {
    const float* support = (const float*)d_in[0];
    const float* query   = (const float*)d_in[1];
    float* out = (float*)d_out;

    char* ws = (char*)d_ws;
    unsigned short* Sn = (unsigned short*)ws;                      //   819,200 B
    unsigned short* Qn = (unsigned short*)(ws + 819200);           // 2,457,600 B
    float* partial     = (float*)(ws + 819200 + 2457600);          // 2,304,000 B (5.58 MB)

    prep    <<<dim3(400),              dim3(256), 0, stream>>>(support, query, Sn, Qn);
    dn4_mfma<<<dim3(C_CLS * NQ * 2),   dim3(512), 0, stream>>>(Sn, Qn, partial);
    dn4_topq<<<dim3(C_CLS * NQ * K1),  dim3(256), 0, stream>>>(partial, out);
}

// Round 10
// 51.248 us; speedup vs baseline: 1.0121x; 1.0121x over previous
//
#include <hip/hip_runtime.h>
#include <stdint.h>

// DN4 image-to-class via bf16 MFMA, round 10: barrier-free register streaming.
// prep:     normalize descriptors into MFMA fragment order (round-9 layout,
//           verified): per 16-descriptor block, 1024 us: [ck][kg*16+row][8].
// dn4_mfma: grid 1500 = (c, M-quarter, b); 4 waves x 64 queries; NO LDS, NO
//           barriers: support fragments stream L2->VGPR (coalesced 1KB/wave
//           loads, 1-step ping-pong prefetch); per-lane top-3 lattices;
//           bitonic triple-merge across the 16 support-column lanes.
// dn4_topq: merge 4 quarters x top-3, shfl-bitonic descending sort 256 -> 64.

#define C_CLS 5
#define SHOTS 5
#define DIM 64
#define HW 256
#define NQ 75
#define K1 3
#define K2 64
#define M_TOT 1280
#define MQ 4                  // M quarters (grid-level split)
#define NSTEP 20              // 16-row fragment blocks per quarter (320 rows)
#define QG 4                  // 16-query groups per wave (64 q/wave)

using bf16x8 = __attribute__((ext_vector_type(8))) short;
using u32x4  = __attribute__((ext_vector_type(4))) unsigned int;
using f32x4  = __attribute__((ext_vector_type(4))) float;

__device__ inline unsigned short f2bf(float x) {
    uint32_t u = __float_as_uint(x);
    u += 0x7FFF + ((u >> 16) & 1);          // RNE
    return (unsigned short)(u >> 16);
}

// branchless sorted-triple insert; t2 reads old t1, t1 reads old t0
__device__ __forceinline__ void ins3(float v, float& t0, float& t1, float& t2) {
    t2 = __builtin_amdgcn_fmed3f(v, t1, t2);
    t1 = __builtin_amdgcn_fmed3f(v, t0, t1);
    t0 = fmaxf(t0, v);
}

// 400 blocks x 256 threads; each wave: 16 descriptors x 4 d-groups of 16.
// Fragment block contract (1024 us per 16 descriptors):
//   us[ck*512 + (kg*16 + row)*8 + j] = elem(row, k = ck*32 + kg*8 + j)
__global__ __launch_bounds__(256)
void prep(const float* __restrict__ support, const float* __restrict__ query,
          unsigned short* __restrict__ Sn, unsigned short* __restrict__ Qn) {
    const int tid  = threadIdx.x;
    const int wv   = tid >> 6, lane = tid & 63;
    const int dg   = lane >> 4, dl = lane & 15;
    const int bid  = blockIdx.x;
    const float* src;
    unsigned short* dstblk;
    if (bid < NQ * 4) {
        const int b    = bid >> 2;
        const int desc = (bid & 3) * 64 + wv * 16 + dl;
        src    = query + (size_t)b * DIM * HW + desc;
        dstblk = Qn + (size_t)b * 16384 + (size_t)((bid & 3) * 4 + wv) * 1024;
    } else {
        const int sb   = bid - NQ * 4;
        const int cs   = sb >> 2;                      // c*SHOTS + s
        const int desc = (sb & 3) * 64 + wv * 16 + dl;
        const int c = cs / SHOTS, s = cs % SHOTS;
        src    = support + (size_t)cs * DIM * HW + desc;
        dstblk = Sn + (size_t)c * 81920 + (size_t)(s * 16 + (sb & 3) * 4 + wv) * 1024;
    }
    float v[16];
    float nrm = 0.f;
#pragma unroll
    for (int i = 0; i < 16; ++i) {
        const float x = src[(dg * 16 + i) * HW];
        v[i] = x; nrm = fmaf(x, x, nrm);
    }
    nrm += __shfl_xor(nrm, 16, 64);
    nrm += __shfl_xor(nrm, 32, 64);
    const float inv = rsqrtf(nrm);
    uint32_t p[8];
#pragma unroll
    for (int j = 0; j < 8; ++j)
        p[j] = (uint32_t)f2bf(v[2 * j] * inv) | ((uint32_t)f2bf(v[2 * j + 1] * inv) << 16);
    const int ck = dg >> 1;
#pragma unroll
    for (int q = 0; q < 2; ++q) {
        const int kg = (dg & 1) * 2 + q;
        uint4 wq = {p[q * 4 + 0], p[q * 4 + 1], p[q * 4 + 2], p[q * 4 + 3]};
        *(uint4*)(dstblk + ck * 512 + (kg * 16 + dl) * 8) = wq;
    }
}

// grid 1500: bid = (c*MQ + qt)*NQ + b. 256 threads = 4 waves x 64 queries.
__global__ __launch_bounds__(256)
void dn4_mfma(const unsigned short* __restrict__ Sn,
              const unsigned short* __restrict__ Qn,
              unsigned short* __restrict__ partial) {
    const int tid  = threadIdx.x;
    const int lane = tid & 63, w = tid >> 6;        // w in 0..3
    const int c15  = lane & 15, kg = lane >> 4;
    const int bid  = blockIdx.x;
    const int b    = bid % NQ;
    const int cq   = bid / NQ;                      // c*MQ + qt
    const int c    = cq >> 2, qt = cq & 3;

    // ---- A fragments: 64 queries, contiguous 1KB wave loads ----
    bf16x8 aq[QG][2];
    const unsigned short* qf = Qn + (size_t)b * 16384 + (size_t)(w * QG) * 1024;
#pragma unroll
    for (int g = 0; g < QG; ++g)
#pragma unroll
        for (int ck = 0; ck < 2; ++ck)
            aq[g][ck] = __builtin_bit_cast(bf16x8,
                *(const u32x4*)(qf + g * 1024 + ck * 512 + lane * 8));

    float t0[QG][4], t1[QG][4], t2[QG][4];
#pragma unroll
    for (int g = 0; g < QG; ++g)
#pragma unroll
        for (int r = 0; r < 4; ++r) { t0[g][r] = -2.f; t1[g][r] = -2.f; t2[g][r] = -2.f; }

    const f32x4 Z = {0.f, 0.f, 0.f, 0.f};
    const unsigned short* sp = Sn + (size_t)c * 81920 + (size_t)qt * (NSTEP * 1024);

    // ---- barrier-free main loop: 20 steps of 16 support rows, 1-deep prefetch ----
    u32x4 p0 = *(const u32x4*)(sp + lane * 8);
    u32x4 p1 = *(const u32x4*)(sp + 512 + lane * 8);
#pragma unroll
    for (int it = 0; it < NSTEP; ++it) {
        u32x4 n0 = p0, n1 = p1;
        if (it + 1 < NSTEP) {                       // static after full unroll
            const unsigned short* rp = sp + (it + 1) * 1024 + lane * 8;
            n0 = *(const u32x4*)rp;
            n1 = *(const u32x4*)(rp + 512);
        }
        const bf16x8 b0 = __builtin_bit_cast(bf16x8, p0);
        const bf16x8 b1 = __builtin_bit_cast(bf16x8, p1);
#pragma unroll
        for (int g = 0; g < QG; ++g) {
            f32x4 acc = __builtin_amdgcn_mfma_f32_16x16x32_bf16(aq[g][0], b0, Z, 0, 0, 0);
            acc = __builtin_amdgcn_mfma_f32_16x16x32_bf16(aq[g][1], b1, acc, 0, 0, 0);
#pragma unroll
            for (int r = 0; r < 4; ++r)
                ins3(acc[r], t0[g][r], t1[g][r], t2[g][r]);
        }
        p0 = n0; p1 = n1;
    }

    // ---- merge across the 16 support-column lanes: bitonic triple-merge ----
#pragma unroll
    for (int g = 0; g < QG; ++g)
#pragma unroll
        for (int r = 0; r < 4; ++r)
#pragma unroll
            for (int off = 1; off < 16; off <<= 1) {
                const float o0 = __shfl_xor(t0[g][r], off, 64);
                const float o1 = __shfl_xor(t1[g][r], off, 64);
                const float o2 = __shfl_xor(t2[g][r], off, 64);
                // both triples sorted desc: top-3 of union = sort of pairwise maxes
                const float x = fmaxf(t0[g][r], o2);
                const float y = fmaxf(t1[g][r], o1);
                const float z = fmaxf(t2[g][r], o0);
                t0[g][r] = fmaxf(fmaxf(x, y), z);
                t1[g][r] = __builtin_amdgcn_fmed3f(x, y, z);
                t2[g][r] = fminf(fminf(x, y), z);
            }

    if (c15 == 0) {
        unsigned short* pbase =
            partial + (((size_t)(c * NQ + b) * MQ + qt) * K1) * HW;
#pragma unroll
        for (int g = 0; g < QG; ++g)
#pragma unroll
            for (int r = 0; r < 4; ++r) {
                const int qloc = (w * QG + g) * 16 + kg * 4 + r;
                pbase[qloc]          = f2bf(t0[g][r]);
                pbase[HW + qloc]     = f2bf(t1[g][r]);
                pbase[2 * HW + qloc] = f2bf(t2[g][r]);
            }
    }
}

// grid 1125: (c*NQ+b)*3 + ki. Merge 4 quarters x top-3, shfl-bitonic sort, write 64.
__global__ __launch_bounds__(256)
void dn4_topq(const unsigned short* __restrict__ partial, float* __restrict__ out) {
    __shared__ float sbuf[HW];
    const int tid = threadIdx.x;
    const int bid = blockIdx.x;
    const int ki  = bid % K1;
    const int cb  = bid / K1;

    const unsigned short* p = partial + (size_t)cb * MQ * K1 * HW + tid;
    float t0 = -2.f, t1 = -2.f, t2 = -2.f;
#pragma unroll
    for (int h = 0; h < MQ; ++h)
#pragma unroll
        for (int r = 0; r < K1; ++r) {
            const float v = __uint_as_float((uint32_t)p[(h * K1 + r) * HW] << 16);
            ins3(v, t0, t1, t2);
        }
    float v = (ki == 0) ? t0 : (ki == 1) ? t1 : t2;

#pragma unroll
    for (int kk = 2; kk <= HW; kk <<= 1) {
#pragma unroll
        for (int j = kk >> 1; j > 0; j >>= 1) {
            const bool keep_max = (((tid & kk) == 0) == ((tid & j) == 0));
            float wv;
            if (j >= 64) {
                sbuf[tid] = v;
                __syncthreads();
                wv = sbuf[tid ^ j];
                __syncthreads();
            } else {
                wv = __shfl_xor(v, j, 64);
            }
            v = keep_max ? fmaxf(v, wv) : fminf(v, wv);
        }
    }
    if (tid < K2) out[(size_t)cb * K1 * K2 + (size_t)ki * K2 + tid] = v;
}

extern "C" void kernel_launch(void* const* d_in, const int* in_sizes, int n_in,
                              void* d_out, int out_size, void* d_ws, size_t ws_size,
                              hipStream_t stream) {
    const float* support = (const float*)d_in[0];
    const float* query   = (const float*)d_in[1];
    float* out = (float*)d_out;

    char* ws = (char*)d_ws;
    unsigned short* Sn      = (unsigned short*)ws;                      //   819,200 B
    unsigned short* Qn      = (unsigned short*)(ws + 819200);           // 2,457,600 B
    unsigned short* partial = (unsigned short*)(ws + 819200 + 2457600); // 2,304,000 B (5.58 MB)

    prep    <<<dim3(400),              dim3(256), 0, stream>>>(support, query, Sn, Qn);
    dn4_mfma<<<dim3(C_CLS * MQ * NQ),  dim3(256), 0, stream>>>(Sn, Qn, partial);
    dn4_topq<<<dim3(C_CLS * NQ * K1),  dim3(256), 0, stream>>>(partial, out);
}

// Round 11
// 49.705 us; speedup vs baseline: 1.0435x; 1.0310x over previous
//
#include <hip/hip_runtime.h>
#include <stdint.h>

// DN4 image-to-class via bf16 MFMA, round 11: r8 structure + r9 fragment layout.
// prep:     normalize descriptors into MFMA fragment order (verified r9/r10):
//           per 16-descriptor block, 1024 us: [ck][kg*16+row][8].
// dn4_mfma: grid 1500 = (c, M-quarter, b); 512 threads = 8 waves x 32 queries;
//           64-row support tiles (4 fragment blocks, 8 KB) double-buffered in
//           LDS via LINEAR global_load_lds (fragment layout: no swizzle needed,
//           ds_reads contiguous); per-lane top-3 lattices; bitonic triple-merge.
// dn4_topq: merge 4 quarters x top-3, shfl-bitonic descending sort 256 -> 64.

#define C_CLS 5
#define SHOTS 5
#define DIM 64
#define HW 256
#define NQ 75
#define K1 3
#define K2 64
#define M_TOT 1280
#define MQ 4                  // M quarters (grid-level split)
#define NIT 5                 // 64-row tiles per quarter (320 rows)
#define QG 2                  // 16-query groups per wave (32 q/wave)

using bf16x8 = __attribute__((ext_vector_type(8))) short;
using u32x4  = __attribute__((ext_vector_type(4))) unsigned int;
using f32x4  = __attribute__((ext_vector_type(4))) float;

typedef __attribute__((address_space(1))) const unsigned int GU32;
typedef __attribute__((address_space(3))) unsigned int LU32;

__device__ __forceinline__ void gload16(const void* g, void* l) {
    __builtin_amdgcn_global_load_lds((GU32*)g, (LU32*)l, 16, 0, 0);
}

__device__ inline unsigned short f2bf(float x) {
    uint32_t u = __float_as_uint(x);
    u += 0x7FFF + ((u >> 16) & 1);          // RNE
    return (unsigned short)(u >> 16);
}

// branchless sorted-triple insert; t2 reads old t1, t1 reads old t0
__device__ __forceinline__ void ins3(float v, float& t0, float& t1, float& t2) {
    t2 = __builtin_amdgcn_fmed3f(v, t1, t2);
    t1 = __builtin_amdgcn_fmed3f(v, t0, t1);
    t0 = fmaxf(t0, v);
}

// 400 blocks x 256 threads; each wave: 16 descriptors x 4 d-groups of 16.
// Fragment block contract (1024 us per 16 descriptors):
//   us[ck*512 + (kg*16 + row)*8 + j] = elem(row, k = ck*32 + kg*8 + j)
__global__ __launch_bounds__(256)
void prep(const float* __restrict__ support, const float* __restrict__ query,
          unsigned short* __restrict__ Sn, unsigned short* __restrict__ Qn) {
    const int tid  = threadIdx.x;
    const int wv   = tid >> 6, lane = tid & 63;
    const int dg   = lane >> 4, dl = lane & 15;
    const int bid  = blockIdx.x;
    const float* src;
    unsigned short* dstblk;
    if (bid < NQ * 4) {
        const int b    = bid >> 2;
        const int desc = (bid & 3) * 64 + wv * 16 + dl;
        src    = query + (size_t)b * DIM * HW + desc;
        dstblk = Qn + (size_t)b * 16384 + (size_t)((bid & 3) * 4 + wv) * 1024;
    } else {
        const int sb   = bid - NQ * 4;
        const int cs   = sb >> 2;                      // c*SHOTS + s
        const int desc = (sb & 3) * 64 + wv * 16 + dl;
        const int c = cs / SHOTS, s = cs % SHOTS;
        src    = support + (size_t)cs * DIM * HW + desc;
        dstblk = Sn + (size_t)c * 81920 + (size_t)(s * 16 + (sb & 3) * 4 + wv) * 1024;
    }
    float v[16];
    float nrm = 0.f;
#pragma unroll
    for (int i = 0; i < 16; ++i) {
        const float x = src[(dg * 16 + i) * HW];
        v[i] = x; nrm = fmaf(x, x, nrm);
    }
    nrm += __shfl_xor(nrm, 16, 64);
    nrm += __shfl_xor(nrm, 32, 64);
    const float inv = rsqrtf(nrm);
    uint32_t p[8];
#pragma unroll
    for (int j = 0; j < 8; ++j)
        p[j] = (uint32_t)f2bf(v[2 * j] * inv) | ((uint32_t)f2bf(v[2 * j + 1] * inv) << 16);
    const int ck = dg >> 1;
#pragma unroll
    for (int q = 0; q < 2; ++q) {
        const int kg = (dg & 1) * 2 + q;
        uint4 wq = {p[q * 4 + 0], p[q * 4 + 1], p[q * 4 + 2], p[q * 4 + 3]};
        *(uint4*)(dstblk + ck * 512 + (kg * 16 + dl) * 8) = wq;
    }
}

// grid 1500: bid = (c*MQ + qt)*NQ + b. 512 threads = 8 waves x 32 queries.
__global__ __launch_bounds__(512)
void dn4_mfma(const unsigned short* __restrict__ Sn,
              const unsigned short* __restrict__ Qn,
              unsigned short* __restrict__ partial) {
    __shared__ unsigned short sB[2][4 * 1024];      // 2 x 8 KB (4 fragment blocks)

    const int tid  = threadIdx.x;
    const int lane = tid & 63, w = tid >> 6;        // w in 0..7
    const int c15  = lane & 15, kg = lane >> 4;
    const int bid  = blockIdx.x;
    const int b    = bid % NQ;
    const int cq   = bid / NQ;                      // c*MQ + qt
    const int c    = cq >> 2, qt = cq & 3;

    // ---- A fragments: contiguous 1KB wave streams (fragment layout) ----
    bf16x8 aq[QG][2];
    const unsigned short* qf = Qn + (size_t)b * 16384 + (size_t)(w * QG) * 1024;
#pragma unroll
    for (int g = 0; g < QG; ++g)
#pragma unroll
        for (int ck = 0; ck < 2; ++ck)
            aq[g][ck] = __builtin_bit_cast(bf16x8,
                *(const u32x4*)(qf + g * 1024 + ck * 512 + lane * 8));

    float t0[QG][4], t1[QG][4], t2[QG][4];
#pragma unroll
    for (int g = 0; g < QG; ++g)
#pragma unroll
        for (int r = 0; r < 4; ++r) { t0[g][r] = -2.f; t1[g][r] = -2.f; t2[g][r] = -2.f; }

    const f32x4 Z = {0.f, 0.f, 0.f, 0.f};
    // this quarter's 20 fragment blocks (40960 B), byte pointer
    const char* tb0 = (const char*)Sn + (size_t)c * 163840 + (size_t)qt * 40960;

    // ---- prologue: stage tile 0 linearly (8 KB = 512 threads x 16 B) ----
    gload16(tb0 + tid * 16, (char*)sB[0] + w * 1024);
    __syncthreads();

    int cur = 0;
    for (int it = 0; it < NIT; ++it) {
        if (it < NIT - 1) {                       // issue next tile BEFORE compute
            const char* tb = tb0 + (size_t)(it + 1) * 8192;
            gload16(tb + tid * 16, (char*)sB[cur ^ 1] + w * 1024);
        }
#pragma unroll
        for (int ns = 0; ns < 4; ++ns) {          // 4 fragment blocks of 16 rows
            const unsigned short* rp = &sB[cur][ns * 1024 + lane * 8];
            const bf16x8 b0 = __builtin_bit_cast(bf16x8, *(const u32x4*)rp);
            const bf16x8 b1 = __builtin_bit_cast(bf16x8, *(const u32x4*)(rp + 512));
#pragma unroll
            for (int g = 0; g < QG; ++g) {
                f32x4 acc = __builtin_amdgcn_mfma_f32_16x16x32_bf16(aq[g][0], b0, Z, 0, 0, 0);
                acc = __builtin_amdgcn_mfma_f32_16x16x32_bf16(aq[g][1], b1, acc, 0, 0, 0);
#pragma unroll
                for (int r = 0; r < 4; ++r)
                    ins3(acc[r], t0[g][r], t1[g][r], t2[g][r]);
            }
        }
        __syncthreads();                          // drains staging vmcnt too
        cur ^= 1;
    }

    // ---- merge across the 16 support-column lanes: bitonic triple-merge ----
#pragma unroll
    for (int g = 0; g < QG; ++g)
#pragma unroll
        for (int r = 0; r < 4; ++r)
#pragma unroll
            for (int off = 1; off < 16; off <<= 1) {
                const float o0 = __shfl_xor(t0[g][r], off, 64);
                const float o1 = __shfl_xor(t1[g][r], off, 64);
                const float o2 = __shfl_xor(t2[g][r], off, 64);
                // both triples sorted desc: top-3 of union = sort of pairwise maxes
                const float x = fmaxf(t0[g][r], o2);
                const float y = fmaxf(t1[g][r], o1);
                const float z = fmaxf(t2[g][r], o0);
                t0[g][r] = fmaxf(fmaxf(x, y), z);
                t1[g][r] = __builtin_amdgcn_fmed3f(x, y, z);
                t2[g][r] = fminf(fminf(x, y), z);
            }

    if (c15 == 0) {
        unsigned short* pbase =
            partial + (((size_t)(c * NQ + b) * MQ + qt) * K1) * HW;
#pragma unroll
        for (int g = 0; g < QG; ++g)
#pragma unroll
            for (int r = 0; r < 4; ++r) {
                const int qloc = (w * QG + g) * 16 + kg * 4 + r;
                pbase[qloc]          = f2bf(t0[g][r]);
                pbase[HW + qloc]     = f2bf(t1[g][r]);
                pbase[2 * HW + qloc] = f2bf(t2[g][r]);
            }
    }
}

// grid 1125: (c*NQ+b)*3 + ki. Merge 4 quarters x top-3, shfl-bitonic sort, write 64.
__global__ __launch_bounds__(256)
void dn4_topq(const unsigned short* __restrict__ partial, float* __restrict__ out) {
    __shared__ float sbuf[HW];
    const int tid = threadIdx.x;
    const int bid = blockIdx.x;
    const int ki  = bid % K1;
    const int cb  = bid / K1;

    const unsigned short* p = partial + (size_t)cb * MQ * K1 * HW + tid;
    float t0 = -2.f, t1 = -2.f, t2 = -2.f;
#pragma unroll
    for (int h = 0; h < MQ; ++h)
#pragma unroll
        for (int r = 0; r < K1; ++r) {
            const float v = __uint_as_float((uint32_t)p[(h * K1 + r) * HW] << 16);
            ins3(v, t0, t1, t2);
        }
    float v = (ki == 0) ? t0 : (ki == 1) ? t1 : t2;

#pragma unroll
    for (int kk = 2; kk <= HW; kk <<= 1) {
#pragma unroll
        for (int j = kk >> 1; j > 0; j >>= 1) {
            const bool keep_max = (((tid & kk) == 0) == ((tid & j) == 0));
            float wv;
            if (j >= 64) {
                sbuf[tid] = v;
                __syncthreads();
                wv = sbuf[tid ^ j];
                __syncthreads();
            } else {
                wv = __shfl_xor(v, j, 64);
            }
            v = keep_max ? fmaxf(v, wv) : fminf(v, wv);
        }
    }
    if (tid < K2) out[(size_t)cb * K1 * K2 + (size_t)ki * K2 + tid] = v;
}

extern "C" void kernel_launch(void* const* d_in, const int* in_sizes, int n_in,
                              void* d_out, int out_size, void* d_ws, size_t ws_size,
                              hipStream_t stream) {
    const float* support = (const float*)d_in[0];
    const float* query   = (const float*)d_in[1];
    float* out = (float*)d_out;

    char* ws = (char*)d_ws;
    unsigned short* Sn      = (unsigned short*)ws;                      //   819,200 B
    unsigned short* Qn      = (unsigned short*)(ws + 819200);           // 2,457,600 B
    unsigned short* partial = (unsigned short*)(ws + 819200 + 2457600); // 2,304,000 B (5.58 MB)

    prep    <<<dim3(400),              dim3(256), 0, stream>>>(support, query, Sn, Qn);
    dn4_mfma<<<dim3(C_CLS * MQ * NQ),  dim3(512), 0, stream>>>(Sn, Qn, partial);
    dn4_topq<<<dim3(C_CLS * NQ * K1),  dim3(256), 0, stream>>>(partial, out);
}